// Round 4
// baseline (98.576 us; speedup 1.0000x reference)
//
#include <hip/hip_runtime.h>

#define BATCH 16
#define HH 512
#define WW 512
#define PLANE (HH*WW)

// Compiler memory-order fences for wave-synchronous LDS exchange.
// HW processes a wave's DS ops in order; these stop the compiler from
// reordering ds_write/ds_read across the cross-lane dependency.
#define LDS_WAIT()   asm volatile("s_waitcnt lgkmcnt(0)" ::: "memory")
#define WAVE_FENCE() asm volatile("" ::: "memory")

// ---------------- K1: guide (channel mean) + 15x15 replicate min-pool ----------------
#define T1 64
#define HALO 7
#define LW (T1 + 2*HALO)   // 78

__global__ __launch_bounds__(256) void k1_guide_minpool(
    const float* __restrict__ smoky, float* __restrict__ guide, float* __restrict__ p)
{
    __shared__ float dcp[LW*LW];     // per-pixel channel min, with replicate halo
    __shared__ float vmn[T1*LW];     // vertical 15-min
    int nwg = gridDim.x;             // 1024, divisible by 8
    int wg = (blockIdx.x & 7) * (nwg >> 3) + (blockIdx.x >> 3);  // XCD-chunked swizzle
    int img  = wg >> 6;              // 64 tiles per image
    int tile = wg & 63;
    int y0 = (tile >> 3) * T1;
    int x0 = (tile & 7) * T1;
    int t = threadIdx.x;
    const float* s0 = smoky + (size_t)img * 3 * PLANE;
    float* gpl = guide + (size_t)img * PLANE;
    float* ppl = p     + (size_t)img * PLANE;

    for (int i = t; i < LW*LW; i += 256) {
        int ly = i / LW, lx = i - ly * LW;
        int iy = y0 - HALO + ly, ix = x0 - HALO + lx;
        int cy = min(max(iy, 0), HH-1);
        int cx = min(max(ix, 0), WW-1);
        const float* bp = s0 + cy * WW + cx;
        float c0 = bp[0], c1 = bp[PLANE], c2 = bp[2*PLANE];
        dcp[i] = fminf(fminf(c0, c1), c2);
        if (ly >= HALO && ly < HALO+T1 && lx >= HALO && lx < HALO+T1)
            gpl[iy * WW + ix] = (c0 + c1 + c2) * (1.0f/3.0f);
    }
    __syncthreads();
    for (int i = t; i < T1*LW; i += 256) {
        int r = i / LW, c = i - r * LW;
        float m = dcp[r*LW + c];
        #pragma unroll
        for (int d = 1; d < 15; ++d) m = fminf(m, dcp[(r+d)*LW + c]);
        vmn[i] = m;
    }
    __syncthreads();
    for (int i = t; i < T1*T1; i += 256) {
        int r = i >> 6, c = i & 63;
        float m = vmn[r*LW + c];
        #pragma unroll
        for (int d = 1; d < 15; ++d) m = fminf(m, vmn[r*LW + c + d]);
        ppl[(y0+r)*WW + x0 + c] = m;
    }
}

// ---------------- K2: wave-autonomous fused box sums (I, I^2, p, I*p) -> interleaved (a,b) ----------------
#define RS2 8

__global__ __launch_bounds__(256) void k2_ab(
    const float* __restrict__ guide, const float* __restrict__ p,
    float2* __restrict__ abO)
{
    __shared__ float ls[4][4][80];   // [wave][quantity][slot]
    int nwg = gridDim.x;             // 2048
    int wg = (blockIdx.x & 7) * (nwg >> 3) + (blockIdx.x >> 3);
    int w = threadIdx.x >> 6, l = threadIdx.x & 63;
    int gw = wg * 4 + w;             // 0..8191
    int img   = gw >> 9;             // 512 waves per image
    int cg    = (gw >> 6) & 7;
    int strip = gw & 63;             // 64 row-strips of 8
    int y0 = strip * RS2;
    int c0 = cg * 64;
    const float* gP = guide + (size_t)img * PLANE;
    const float* pP = p     + (size_t)img * PLANE;
    float2* abP = abO + (size_t)img * PLANE;

    int col0 = c0 - 7 + l;      // slot l
    int col1 = c0 + 57 + l;     // slot 64+l (lanes 0..13)
    bool v0 = (col0 >= 0);
    bool v1 = (l < 14) && (col1 < WW);

    float sI0=0,sII0=0,sP0=0,sIp0=0;
    float sI1=0,sII1=0,sP1=0,sIp1=0;

    auto loadrow = [&](int y, float& I0, float& Q0, float& I1, float& Q1) {
        I0 = 0.f; Q0 = 0.f; I1 = 0.f; Q1 = 0.f;
        if ((unsigned)y < (unsigned)HH) {
            const float* gr = gP + (size_t)y * WW;
            const float* pr = pP + (size_t)y * WW;
            if (v0) { I0 = gr[col0]; Q0 = pr[col0]; }
            if (v1) { I1 = gr[col1]; Q1 = pr[col1]; }
        }
    };

    // warm-up: window = rows [y0-8, y0+6]
    for (int r = y0 - 8; r <= y0 + 6; ++r) {
        float I0,Q0,I1,Q1; loadrow(r, I0,Q0,I1,Q1);
        sI0+=I0; sII0+=I0*I0; sP0+=Q0; sIp0+=I0*Q0;
        sI1+=I1; sII1+=I1*I1; sP1+=Q1; sIp1+=I1*Q1;
    }

    float* L = &ls[w][0][0];
    const float inv225 = 1.0f/225.0f;

    auto emit = [&](int y) {
        L[l] = sI0; L[80+l] = sII0; L[160+l] = sP0; L[240+l] = sIp0;
        if (l < 14) { L[64+l] = sI1; L[144+l] = sII1; L[224+l] = sP1; L[304+l] = sIp1; }
        LDS_WAIT();
        float SI=0,SII=0,SP=0,SIp=0;
        #pragma unroll
        for (int d = 0; d < 15; ++d) {
            SI  += L[l+d];
            SII += L[80+l+d];
            SP  += L[160+l+d];
            SIp += L[240+l+d];
        }
        WAVE_FENCE();   // keep next iter's ds_writes below this iter's ds_reads
        float mI = SI*inv225, mP = SP*inv225;
        float va = (SIp*inv225 - mI*mP) / (SII*inv225 - mI*mI + 1e-3f);
        abP[(size_t)y*WW + c0 + l] = make_float2(va, mP - va*mI);
    };

    // 2-deep pipeline: set A feeds iter y, set B feeds iter y+1
    float aI0A,aQ0A,aI1A,aQ1A, bI0A,bQ0A,bI1A,bQ1A;
    float aI0B,aQ0B,aI1B,aQ1B, bI0B,bQ0B,bI1B,bQ1B;
    loadrow(y0 + 7, aI0A,aQ0A,aI1A,aQ1A);
    loadrow(y0 - 8, bI0A,bQ0A,bI1A,bQ1A);
    loadrow(y0 + 8, aI0B,aQ0B,aI1B,aQ1B);
    loadrow(y0 - 7, bI0B,bQ0B,bI1B,bQ1B);

    for (int y = y0; y < y0 + RS2; y += 2) {
        // even iter: consume set A, issue loads for iter y+2
        sI0 += aI0A - bI0A;  sII0 += aI0A*aI0A - bI0A*bI0A;
        sP0 += aQ0A - bQ0A;  sIp0 += aI0A*aQ0A - bI0A*bQ0A;
        sI1 += aI1A - bI1A;  sII1 += aI1A*aI1A - bI1A*bI1A;
        sP1 += aQ1A - bQ1A;  sIp1 += aI1A*aQ1A - bI1A*bQ1A;
        loadrow(y + 9, aI0A,aQ0A,aI1A,aQ1A);
        loadrow(y - 6, bI0A,bQ0A,bI1A,bQ1A);
        emit(y);
        // odd iter: consume set B, issue loads for iter y+3
        sI0 += aI0B - bI0B;  sII0 += aI0B*aI0B - bI0B*bI0B;
        sP0 += aQ0B - bQ0B;  sIp0 += aI0B*aQ0B - bI0B*bQ0B;
        sI1 += aI1B - bI1B;  sII1 += aI1B*aI1B - bI1B*bI1B;
        sP1 += aQ1B - bQ1B;  sIp1 += aI1B*aQ1B - bI1B*bQ1B;
        loadrow(y + 10, aI0B,aQ0B,aI1B,aQ1B);
        loadrow(y - 5,  bI0B,bQ0B,bI1B,bQ1B);
        emit(y + 1);
    }
}

// ---------------- K3: wave-autonomous box sums of (a,b) + guided output + combine ----------------
__global__ __launch_bounds__(256) void k3_final(
    const float2* __restrict__ abI, const float* __restrict__ guide,
    const float* __restrict__ smoky, const float* __restrict__ rho,
    float* __restrict__ out)
{
    __shared__ float ls[4][2][80];
    int nwg = gridDim.x;             // 2048
    int wg = (blockIdx.x & 7) * (nwg >> 3) + (blockIdx.x >> 3);
    int w = threadIdx.x >> 6, l = threadIdx.x & 63;
    int gw = wg * 4 + w;
    int img   = gw >> 9;
    int cg    = (gw >> 6) & 7;
    int strip = gw & 63;
    int y0 = strip * RS2;
    int c0 = cg * 64;
    const float2* abP = abI + (size_t)img * PLANE;
    const float* gP = guide + (size_t)img * PLANE;
    const float* sP = smoky + (size_t)img * 3 * PLANE;
    const float* rP = rho   + (size_t)img * 3 * PLANE;
    float* oP = out + (size_t)img * 3 * PLANE;

    int col0 = c0 - 7 + l;
    int col1 = c0 + 57 + l;
    bool v0 = (col0 >= 0);
    bool v1 = (l < 14) && (col1 < WW);

    float sa0=0, sb0=0, sa1=0, sb1=0;

    auto loadrow = [&](int y, float2& P0, float2& P1) {
        P0 = make_float2(0.f, 0.f); P1 = make_float2(0.f, 0.f);
        if ((unsigned)y < (unsigned)HH) {
            const float2* r = abP + (size_t)y * WW;
            if (v0) P0 = r[col0];
            if (v1) P1 = r[col1];
        }
    };

    for (int r = y0 - 8; r <= y0 + 6; ++r) {
        float2 P0, P1; loadrow(r, P0, P1);
        sa0 += P0.x; sb0 += P0.y; sa1 += P1.x; sb1 += P1.y;
    }

    int yend = y0 + RS2;
    auto loademit = [&](int y, float& eg, float& es0, float& es1, float& es2,
                        float& er0, float& er1, float& er2) {
        if (y < yend) {
            size_t off = (size_t)y*WW + c0 + l;
            eg  = gP[off];
            es0 = sP[off]; es1 = sP[off+PLANE]; es2 = sP[off+2*PLANE];
            er0 = rP[off]; er1 = rP[off+PLANE]; er2 = rP[off+2*PLANE];
        }
    };

    float* L = &ls[w][0][0];
    const float inv225 = 1.0f/225.0f;
    const float inv11  = 1.0f/1.1f;

    auto emit = [&](int y, float g, float s0, float s1, float s2,
                    float r0, float r1, float r2) {
        L[l] = sa0; L[80+l] = sb0;
        if (l < 14) { L[64+l] = sa1; L[144+l] = sb1; }
        LDS_WAIT();
        float SA=0, SB=0;
        #pragma unroll
        for (int d = 0; d < 15; ++d) { SA += L[l+d]; SB += L[80+l+d]; }
        WAVE_FENCE();
        float dcr = SA*inv225*g + SB*inv225;
        float f = (0.1f + dcr) * inv11;
        size_t off = (size_t)y*WW + c0 + l;
        oP[off]          = s0 - f*(1.0f - r0);
        oP[off+PLANE]    = s1 - f*(1.0f - r1);
        oP[off+2*PLANE]  = s2 - f*(1.0f - r2);
    };

    // 2-deep pipeline
    float2 addA0, addA1, subA0, subA1;
    float2 addB0, addB1, subB0, subB1;
    float egA,esA0,esA1,esA2,erA0,erA1,erA2;
    float egB,esB0,esB1,esB2,erB0,erB1,erB2;
    loadrow(y0 + 7, addA0, addA1);
    loadrow(y0 - 8, subA0, subA1);
    loademit(y0, egA,esA0,esA1,esA2,erA0,erA1,erA2);
    loadrow(y0 + 8, addB0, addB1);
    loadrow(y0 - 7, subB0, subB1);
    loademit(y0 + 1, egB,esB0,esB1,esB2,erB0,erB1,erB2);

    for (int y = y0; y < yend; y += 2) {
        // even iter: consume set A, issue for y+2
        sa0 += addA0.x - subA0.x;  sb0 += addA0.y - subA0.y;
        sa1 += addA1.x - subA1.x;  sb1 += addA1.y - subA1.y;
        float g = egA, s0 = esA0, s1 = esA1, s2 = esA2;
        float r0 = erA0, r1 = erA1, r2 = erA2;
        loadrow(y + 9, addA0, addA1);
        loadrow(y - 6, subA0, subA1);
        loademit(y + 2, egA,esA0,esA1,esA2,erA0,erA1,erA2);
        emit(y, g, s0, s1, s2, r0, r1, r2);
        // odd iter: consume set B, issue for y+3
        sa0 += addB0.x - subB0.x;  sb0 += addB0.y - subB0.y;
        sa1 += addB1.x - subB1.x;  sb1 += addB1.y - subB1.y;
        g = egB; s0 = esB0; s1 = esB1; s2 = esB2;
        r0 = erB0; r1 = erB1; r2 = erB2;
        loadrow(y + 10, addB0, addB1);
        loadrow(y - 5,  subB0, subB1);
        loademit(y + 3, egB,esB0,esB1,esB2,erB0,erB1,erB2);
        emit(y + 1, g, s0, s1, s2, r0, r1, r2);
    }
}

extern "C" void kernel_launch(void* const* d_in, const int* in_sizes, int n_in,
                              void* d_out, int out_size, void* d_ws, size_t ws_size,
                              hipStream_t stream) {
    const float* smoky = (const float*)d_in[0];
    const float* rho   = (const float*)d_in[1];
    float* out = (float*)d_out;
    float* ws  = (float*)d_ws;
    const size_t P = (size_t)BATCH * PLANE;
    float* guide = ws;
    float* p     = ws + P;
    float2* ab   = (float2*)(ws + 2*P);   // interleaved (a,b): 2P floats

    k1_guide_minpool<<<BATCH*64, 256, 0, stream>>>(smoky, guide, p);
    k2_ab<<<BATCH*128, 256, 0, stream>>>(guide, p, ab);
    k3_final<<<BATCH*128, 256, 0, stream>>>(ab, guide, smoky, rho, out);
}